// Round 6
// baseline (186.076 us; speedup 1.0000x reference)
//
#include <hip/hip_runtime.h>
#include <hip/hip_bf16.h>

typedef __attribute__((ext_vector_type(8))) short short8;
typedef __attribute__((ext_vector_type(4))) short short4v;
typedef __attribute__((ext_vector_type(4))) float f32x4;

namespace {
constexpr int D    = 128;
constexpr int SEQ  = 512;
constexpr int NV   = 100000;
constexpr int NN   = 2048;
constexpr int KC   = 64;                     // keys per LDS chunk
constexpr int CHUNK_B = KC * D * 2;          // 16384 B
constexpr int CPS     = 25;                  // chunks per V-slice (uniform, padded)
constexpr int NSLICE  = 63;                  // 63*25*64 = 100800 >= NV
constexpr int MBLKS   = 8;                   // M blocks of 256 rows
constexpr int GRID    = MBLKS * NSLICE;      // 504 blocks = 2 blocks/CU resident
constexpr float LOG2E = 1.4426950408889634f;
constexpr float EPSN  = 1e-12f;
}

// ---------------------------------------------------------------------------
// Prep (fused with tgt): normalize keys -> bf16 Kn[V][128]; gather+normalize
// queries scaled by log2(e) -> bf16 Qn[N][128]; for query rows ALSO compute
// tgt[n] = <q_n,k_label>/(|q||k|) in fp32 (r5 lesson: the separate tgt
// launch buys nothing). Also zeroes sums[] and the completion counter
// (replaces hipMemsetAsync). 2 rows/wave, float4 loads.
// ---------------------------------------------------------------------------
__global__ __launch_bounds__(256)
void prep_kernel(const float* __restrict__ qemb,
                 const float* __restrict__ kemb,
                 const int*   __restrict__ loc,
                 const int*   __restrict__ labels,
                 __hip_bfloat16* __restrict__ Kn,
                 __hip_bfloat16* __restrict__ Qn,
                 float* __restrict__ tgt,
                 float* __restrict__ sums,
                 unsigned int* __restrict__ counter)
{
    const int gid = blockIdx.x * blockDim.x + threadIdx.x;
    if (gid < NN) sums[gid] = 0.f;
    if (gid == NN) *counter = 0u;

    const int gw   = gid >> 6;
    const int lane = threadIdx.x & 63;
    const int half = lane >> 5;          // which of the wave's 2 rows
    const int l32  = lane & 31;
    const int row  = gw * 2 + half;      // NV even -> no K/Q straddle in a wave
    if (row >= NV + NN) return;

    if (row < NV) {                      // ---- key row ----
        const float* src = kemb + (size_t)row * D;
        float4 v = *(const float4*)(src + l32 * 4);
        float ss = v.x * v.x + v.y * v.y + v.z * v.z + v.w * v.w;
        #pragma unroll
        for (int m = 1; m < 32; m <<= 1) ss += __shfl_xor(ss, m);
        float inv = 1.0f / fmaxf(sqrtf(ss), EPSN);
        union { __hip_bfloat162 h2[2]; short4v s4; } u;
        u.h2[0].x = __float2bfloat16(v.x * inv);
        u.h2[0].y = __float2bfloat16(v.y * inv);
        u.h2[1].x = __float2bfloat16(v.z * inv);
        u.h2[1].y = __float2bfloat16(v.w * inv);
        *(short4v*)((char*)(Kn + (size_t)row * D) + l32 * 8) = u.s4;
    } else {                             // ---- query row (+ tgt) ----
        const int n = row - NV;
        const int b = loc[2 * n], s = loc[2 * n + 1];
        const float* q = qemb + ((size_t)b * SEQ + s) * D;
        const float* k = kemb + (size_t)labels[n] * D;
        float4 qv = *(const float4*)(q + l32 * 4);
        float4 kv = *(const float4*)(k + l32 * 4);
        float qq = qv.x * qv.x + qv.y * qv.y + qv.z * qv.z + qv.w * qv.w;
        float kk = kv.x * kv.x + kv.y * kv.y + kv.z * kv.z + kv.w * kv.w;
        float qk = qv.x * kv.x + qv.y * kv.y + qv.z * kv.z + qv.w * kv.w;
        #pragma unroll
        for (int m = 1; m < 32; m <<= 1) {
            qq += __shfl_xor(qq, m);
            kk += __shfl_xor(kk, m);
            qk += __shfl_xor(qk, m);
        }
        float invq = 1.0f / fmaxf(sqrtf(qq), EPSN);
        float scl  = LOG2E * invq;
        union { __hip_bfloat162 h2[2]; short4v s4; } u;
        u.h2[0].x = __float2bfloat16(qv.x * scl);
        u.h2[0].y = __float2bfloat16(qv.y * scl);
        u.h2[1].x = __float2bfloat16(qv.z * scl);
        u.h2[1].y = __float2bfloat16(qv.w * scl);
        *(short4v*)((char*)(Qn + (size_t)n * D) + l32 * 8) = u.s4;
        if (l32 == 0)
            tgt[n] = qk * invq / fmaxf(sqrtf(kk), EPSN);
    }
}

// ---------------------------------------------------------------------------
// Main. 256 threads = 4 waves; each wave owns 64 Q-rows (qf[4][4] = 64 VGPR)
// -> LDS traffic HALVED vs r5 (32 row-waves x 25.6 MB = 820 MB total; r5's
// 67us was LDS-read-bound at 1.64 GB). __launch_bounds__(256,2): 256-VGPR
// budget, guaranteed no spill (r1-r3 lesson; tripwire = WRITE_SIZE).
// 4-buffer LDS ring (64 KB), depth-3 prefetch via global_load_lds (linear
// LDS dest, inverse-swizzled source; read phys = logical ^ ((keyrow&7)<<4)),
// counted vmcnt(8/4/0) tail. Slices uniform CPS=25 (keys padded: loads
// clamped to NV-1, exp2 masked by column validity). Grid 504 <= 512 resident.
// XCD swizzle co-locates a slice's 8 M-blocks (r4: FETCH 208->15 MB).
// Last-finished block (ticket) computes the final mean inline.
// ---------------------------------------------------------------------------
__global__ __launch_bounds__(256, 2)
void lse_main(const __hip_bfloat16* __restrict__ Kn,
              const __hip_bfloat16* __restrict__ Qn,
              const float* __restrict__ tgt,
              float* __restrict__ sums,
              unsigned int* __restrict__ counter,
              float* __restrict__ out)
{
    __shared__ char lds[4 * CHUNK_B];   // 64 KB -> 2 blocks/CU
    const int tid  = threadIdx.x;
    const int lane = tid & 63;
    const int lr   = lane & 15;
    const int lh   = lane >> 4;
    const int w    = tid >> 6;          // wave 0..3

    // XCD-aware decode: consecutive bids (same XCD via %8 dispatch) get
    // consecutive lins -> the 8 mblk-blocks of a slice share an XCD.
    const int bid = blockIdx.x;
    const int lin = (bid & 7) * NSLICE + (bid >> 3);
    const int slice = lin >> 3;
    const int mblk  = lin & 7;

    const int chunk0 = slice * CPS;
    const int m0 = mblk * 256 + w * 64;
    const char* kbase = (const char*)Kn;

    // async stage of chunk c into ring buffer bi: LDS linear dest,
    // source pre-swizzled (rule #21: both-sides-or-neither).
    auto stage = [&](int c, int bi) {
        const int keybase = (chunk0 + c) * KC;
        #pragma unroll
        for (int r = 0; r < 4; ++r) {
            const int i   = w * 4 + r;          // 1KB-slab index, wave-uniform
            const int kic = i * 4 + lh;         // key row within chunk (per-lane)
            const int key = min(keybase + kic, NV - 1);
            const int sb  = (lr ^ (kic & 7)) << 4;   // inverse-swizzled byte-in-row
            const char* g = kbase + (size_t)key * 256 + sb;
            const char* l = lds + bi * CHUNK_B + i * 1024;  // wave-uniform base
            __builtin_amdgcn_global_load_lds(
                (const __attribute__((address_space(1))) void*)g,
                (__attribute__((address_space(3))) void*)l, 16, 0, 0);
        }
    };

    stage(0, 0); stage(1, 1); stage(2, 2);     // prologue depth-3

    // A-operand (Q) fragments: rows m0+rg*16+lr, k = ds*32 + lh*8 .. +8
    short8 qf[4][4];
    #pragma unroll
    for (int rg = 0; rg < 4; ++rg)
        #pragma unroll
        for (int ds = 0; ds < 4; ++ds)
            qf[rg][ds] = *(const short8*)((const short*)Qn +
                          (size_t)(m0 + rg * 16 + lr) * D + ds * 32 + lh * 8);

    float rowsum[4][4] = {};
    __syncthreads();   // one-time full drain (prologue stages + qf)

    for (int c = 0; c < CPS; ++c) {
        if (c + 3 < CPS) stage(c + 3, (c + 3) & 3);   // depth-3 prefetch

        const char* buf = lds + (c & 3) * CHUNK_B;
        const int vbase = (chunk0 + c) * KC;
        const bool full = (vbase + KC <= NV);
        #pragma unroll
        for (int kg = 0; kg < 4; ++kg) {
            const int kic = kg * 16 + lr;       // key row within chunk
            const int rx  = (kic & 7) << 4;
            f32x4 acc[4] = {{0,0,0,0},{0,0,0,0},{0,0,0,0},{0,0,0,0}};
            #pragma unroll
            for (int ds2 = 0; ds2 < 4; ++ds2) {
                short8 bf = *(const short8*)(buf +
                              ((kic * 256 + ds2 * 64 + lh * 16) ^ rx));
                #pragma unroll
                for (int rg = 0; rg < 4; ++rg)
                    acc[rg] = __builtin_amdgcn_mfma_f32_16x16x32_bf16(
                                  qf[rg][ds2], bf, acc[rg], 0, 0, 0);
            }
            if (full) {
                #pragma unroll
                for (int rg = 0; rg < 4; ++rg)
                    #pragma unroll
                    for (int j = 0; j < 4; ++j)
                        rowsum[rg][j] += __builtin_amdgcn_exp2f(acc[rg][j]);
            } else {
                const bool ok = (vbase + kic) < NV;   // col = lr on output
                #pragma unroll
                for (int rg = 0; rg < 4; ++rg)
                    #pragma unroll
                    for (int j = 0; j < 4; ++j)
                        rowsum[rg][j] += ok ? __builtin_amdgcn_exp2f(acc[rg][j]) : 0.f;
            }
        }
        // counted wait (T4): stage(c+1) must be done before next iter reads
        // it; deeper prefetches stay in flight across the barrier. Tail
        // iterations need tighter counts because no new stage was issued.
        if (c < CPS - 3) {
            asm volatile("s_waitcnt vmcnt(8)" ::: "memory");
            __builtin_amdgcn_s_barrier();
            asm volatile("" ::: "memory");
        } else if (c == CPS - 3) {
            asm volatile("s_waitcnt vmcnt(4)" ::: "memory");
            __builtin_amdgcn_s_barrier();
            asm volatile("" ::: "memory");
        } else if (c == CPS - 2) {
            asm volatile("s_waitcnt vmcnt(0)" ::: "memory");
            __builtin_amdgcn_s_barrier();
            asm volatile("" ::: "memory");
        }   // c == CPS-1: no further LDS reuse, no wait needed
    }

    // reduce partial sums across the 16 column-lanes, one atomic per row
    #pragma unroll
    for (int rg = 0; rg < 4; ++rg)
        #pragma unroll
        for (int j = 0; j < 4; ++j) {
            float v = rowsum[rg][j];
            v += __shfl_xor(v, 1);
            v += __shfl_xor(v, 2);
            v += __shfl_xor(v, 4);
            v += __shfl_xor(v, 8);
            if (lr == 0)
                atomicAdd(&sums[m0 + rg * 16 + lh * 4 + j], v);
        }

    // ---- last-block final reduction (fuses the old final_kernel) ----
    __threadfence();                       // my atomics visible before ticket
    __syncthreads();
    __shared__ int ticket_s;
    if (tid == 0) ticket_s = (int)atomicAdd(counter, 1u);
    __syncthreads();
    if (ticket_s == GRID - 1) {
        __threadfence();
        __shared__ float wsum[4];
        float acc = 0.f;
        for (int n = tid; n < NN; n += 256) {
            float sv = __hip_atomic_load(&sums[n], __ATOMIC_RELAXED,
                                         __HIP_MEMORY_SCOPE_AGENT);
            acc += logf(sv) - tgt[n];
        }
        #pragma unroll
        for (int m = 1; m < 64; m <<= 1) acc += __shfl_xor(acc, m);
        if ((tid & 63) == 0) wsum[tid >> 6] = acc;
        __syncthreads();
        if (tid == 0)
            out[0] = (wsum[0] + wsum[1] + wsum[2] + wsum[3]) / (float)NN;
    }
}

// ---------------------------------------------------------------------------
extern "C" void kernel_launch(void* const* d_in, const int* in_sizes, int n_in,
                              void* d_out, int out_size, void* d_ws, size_t ws_size,
                              hipStream_t stream)
{
    const float* qemb   = (const float*)d_in[0];
    const float* kemb   = (const float*)d_in[1];
    const int*   loc    = (const int*)d_in[2];
    const int*   labels = (const int*)d_in[3];
    float* out = (float*)d_out;

    char* ws = (char*)d_ws;
    __hip_bfloat16* Kn = (__hip_bfloat16*)ws;
    size_t off = (size_t)NV * D * 2;                       // 25.6 MB
    __hip_bfloat16* Qn = (__hip_bfloat16*)(ws + off);
    off += (size_t)NN * D * 2;                             // +0.5 MB
    float* sums = (float*)(ws + off); off += (size_t)NN * 4;
    float* tgt  = (float*)(ws + off); off += (size_t)NN * 4;
    unsigned int* counter = (unsigned int*)(ws + off);

    {
        int waves  = (NV + NN + 1) / 2;        // 2 rows per wave
        int blocks = (waves + 3) / 4;
        prep_kernel<<<blocks, 256, 0, stream>>>(qemb, kemb, loc, labels,
                                                Kn, Qn, tgt, sums, counter);
    }
    lse_main<<<GRID, 256, 0, stream>>>(Kn, Qn, tgt, sums, counter, out);
}